// Round 10
// baseline (107.606 us; speedup 1.0000x reference)
//
#include <hip/hip_runtime.h>
#include <hip/hip_bf16.h>

#define EPSW 1e-6f

typedef __attribute__((ext_vector_type(4))) float floatx4;
typedef __attribute__((ext_vector_type(8))) short shortx8;   // 8 bf16 (4 VGPRs)

// pack 8 fp32 -> 8 bf16 (round-half-up: +0x8000, hi16 via v_perm).
// <=0.5 ulp vs RNE; absmax-validated rounds 3/5/7/8/9.
__device__ __forceinline__ shortx8 pack8(floatx4 a, floatx4 b) {
    union { shortx8 v; unsigned int u[4]; } r;
    const unsigned a0 = __float_as_uint(a.x) + 0x8000u, a1 = __float_as_uint(a.y) + 0x8000u;
    const unsigned a2 = __float_as_uint(a.z) + 0x8000u, a3 = __float_as_uint(a.w) + 0x8000u;
    const unsigned b0 = __float_as_uint(b.x) + 0x8000u, b1 = __float_as_uint(b.y) + 0x8000u;
    const unsigned b2 = __float_as_uint(b.z) + 0x8000u, b3 = __float_as_uint(b.w) + 0x8000u;
    r.u[0] = __builtin_amdgcn_perm(a1, a0, 0x07060302u);
    r.u[1] = __builtin_amdgcn_perm(a3, a2, 0x07060302u);
    r.u[2] = __builtin_amdgcn_perm(b1, b0, 0x07060302u);
    r.u[3] = __builtin_amdgcn_perm(b3, b2, 0x07060302u);
    return r.v;
}

// ---------------------------------------------------------------------------
// prep_M: 16 blocks x 256 threads (~1-2 us). Each block redundantly builds A
// (normalized adjacency, 4096 edge-ops in LDS — VALU-cheap) then writes one
// 4-column slice of Mt[c][n] = (A@A)[n][c].  (r8-validated pattern.)
// ---------------------------------------------------------------------------
__global__ __launch_bounds__(256) void prep_M(const int* __restrict__ ei,
                                              const float* __restrict__ ew,
                                              float* __restrict__ Mt) {
    __shared__ float A[4096];
    __shared__ float deg[64];
    __shared__ float dinv[64];
    const int bid = blockIdx.x;
    const int t   = threadIdx.x;
    if (t < 64) deg[t] = 1.0f;             // self-loop pre-added
    for (int i = t; i < 4096; i += 256) A[i] = 0.0f;
    __syncthreads();
    const int* srcp = ei;
    const int* dstp = ei + 4096;
#pragma unroll
    for (int i = 0; i < 16; ++i) {
        const int e = i * 256 + t;
        float w = ew[e];
        w = (w <= 0.0f) ? EPSW : w;
        atomicAdd(&deg[dstp[e]], w);
    }
    __syncthreads();
    if (t < 64) dinv[t] = 1.0f / sqrtf(deg[t]);
    __syncthreads();
#pragma unroll
    for (int i = 0; i < 16; ++i) {
        const int e = i * 256 + t;
        float w = ew[e];
        w = (w <= 0.0f) ? EPSW : w;
        const int s = srcp[e], d = dstp[e];
        atomicAdd(&A[d * 64 + s], dinv[s] * w * dinv[d]);
    }
    if (t < 64) atomicAdd(&A[t * 64 + t], dinv[t] * dinv[t]);
    __syncthreads();
    const int c = bid * 4 + (t >> 6);
    const int n = t & 63;
    float s = 0.0f;
#pragma unroll 8
    for (int k = 0; k < 64; ++k) s += A[n * 64 + k] * A[k * 64 + c];
    Mt[c * 64 + n] = s;
}

// ---------------------------------------------------------------------------
// gemm_fused: round-7's MEASURED main loop (44.7 us incl. ~20 us prologue ->
// expected ~25 us here) with the M-prologue removed (Ms staged from global
// Mt under the loop's shadow) and LDS stride fixed 136->132 shorts (row-to-
// row bank offset 2 -> b128 stores and fragment reads bank-balanced).
// 256 blocks x 512 threads; block bid = ht*32 + b (bid%8==b%8: XCD pinning).
// Main: 16 K-chunks of 128, double-buffered LDS staging of x (64 rows) and
// W (16 rows) with inline pack8; 8 waves = (rt 0..3) x (kh 0..1), 2 MFMA
// per chunk per wave.
// Epilogue: kh-reduce via zs[64][17] + y = M.z + bias (r5-validated).
// ---------------------------------------------------------------------------
#define XSTR 132   // 128 + 4 pad shorts; 66 floats/row = 2-bank row skew

__global__ __launch_bounds__(512) void gemm_fused(
        const float* __restrict__ x, const float* __restrict__ W,
        const float* __restrict__ Mt, const float* __restrict__ bias,
        float* __restrict__ y) {
    __shared__ __align__(16) unsigned short smem[29312];
    unsigned short* xs0 = smem;                 // 64*132 = 8448 shorts
    unsigned short* xs1 = smem + 8448;
    unsigned short* ww0 = smem + 16896;         // 16*132 = 2112 shorts
    unsigned short* ww1 = smem + 19008;
    float* Ms = (float*)(smem + 21120);         // 4096 f (disjoint)
    float(*zs)[17] = (float(*)[17])smem;        // overlay xs0 (epilogue)

    const int t   = threadIdx.x;
    const int bid = blockIdx.x;
    const int b   = bid & 31;
    const int ht  = bid >> 5;
    const int wave = t >> 6, lane = t & 63;
    const int m = lane & 15, q = lane >> 4;
    const int rt = wave & 3, kh = wave >> 2;

    // stage Ms from global (issued first; completes under the MFMA loop)
    {
        const floatx4* Mg4 = (const floatx4*)Mt;
        floatx4* Ms4 = (floatx4*)Ms;
        Ms4[t]       = Mg4[t];
        Ms4[t + 512] = Mg4[t + 512];
    }

    const float* xb = x + (size_t)b * 64 * 2000;
    const float* Wb = W + (size_t)ht * 16 * 2000;

    // staging coords: x = 1024 granules-of-8 (2/thread), W = 256 (t<256)
    const int xr0 = t >> 4,         xk0 = (t & 15) * 8;
    const int xr1 = (t + 512) >> 4, xk1 = xk0;
    const int wr  = t >> 4,         wk  = (t & 15) * 8;

    floatx4 px0a, px0b, px1a, px1b, pwa, pwb;
    const floatx4 zero4 = (floatx4){0.f, 0.f, 0.f, 0.f};

#define LOAD_CHUNK(kbase)                                                     \
    {                                                                         \
        const int k0 = (kbase) + xk0;                                         \
        if (k0 < 2000) {                                                      \
            px0a = *(const floatx4*)(xb + (size_t)xr0 * 2000 + k0);           \
            px0b = *(const floatx4*)(xb + (size_t)xr0 * 2000 + k0 + 4);       \
            px1a = *(const floatx4*)(xb + (size_t)xr1 * 2000 + k0);           \
            px1b = *(const floatx4*)(xb + (size_t)xr1 * 2000 + k0 + 4);       \
        } else { px0a = zero4; px0b = zero4; px1a = zero4; px1b = zero4; }    \
        if (t < 256) {                                                        \
            const int kw = (kbase) + wk;                                      \
            if (kw < 2000) {                                                  \
                pwa = *(const floatx4*)(Wb + (size_t)wr * 2000 + kw);         \
                pwb = *(const floatx4*)(Wb + (size_t)wr * 2000 + kw + 4);     \
            } else { pwa = zero4; pwb = zero4; }                              \
        }                                                                     \
    }

    LOAD_CHUNK(0);

    floatx4 acc0 = zero4, acc1 = zero4;
    for (int c = 0; c < 16; ++c) {
        unsigned short* xsb = (c & 1) ? xs1 : xs0;
        unsigned short* wwb = (c & 1) ? ww1 : ww0;
        *(shortx8*)&xsb[xr0 * XSTR + xk0] = pack8(px0a, px0b);
        *(shortx8*)&xsb[xr1 * XSTR + xk1] = pack8(px1a, px1b);
        if (t < 256) *(shortx8*)&wwb[wr * XSTR + wk] = pack8(pwa, pwb);
        __syncthreads();
        if (c < 15) LOAD_CHUNK((c + 1) * 128);
        // 2 MFMA per wave: K window kh*64 + {0,32} + q*8
        const unsigned short* xrow = &xsb[(rt * 16 + m) * XSTR + kh * 64 + q * 8];
        const unsigned short* wrow = &wwb[m * XSTR + kh * 64 + q * 8];
        const shortx8 a0 = *(const shortx8*)xrow;
        const shortx8 b0 = *(const shortx8*)wrow;
        const shortx8 a1 = *(const shortx8*)(xrow + 32);
        const shortx8 b1 = *(const shortx8*)(wrow + 32);
        acc0 = __builtin_amdgcn_mfma_f32_16x16x32_bf16(a0, b0, acc0, 0, 0, 0);
        acc1 = __builtin_amdgcn_mfma_f32_16x16x32_bf16(a1, b1, acc1, 0, 0, 0);
        __syncthreads();
    }
    acc0 += acc1;

    // ===== kh-reduce + apply M + bias (r5-validated) =====
    // C/D layout: row = q*4+v, col = m. zs[64][17] overlays xs0 (safe: last
    // xs0 read was chunk 14, covered by chunk 15's loop-end barrier).
    if (kh == 0) {
#pragma unroll
        for (int v = 0; v < 4; ++v) zs[rt * 16 + q * 4 + v][m] = acc0[v];
    }
    __syncthreads();
    if (kh == 1) {
#pragma unroll
        for (int v = 0; v < 4; ++v) zs[rt * 16 + q * 4 + v][m] += acc0[v];
    }
    __syncthreads();
    {
        const int n0 = t >> 4;        // 0..31
        const int h  = t & 15;
        const float bv = bias[ht * 16 + h];
        float s0 = bv, s1 = bv;
#pragma unroll
        for (int mm = 0; mm < 64; ++mm) {
            const float zv = zs[mm][h];                 // 16-lane broadcast
            s0 += Ms[mm * 64 + n0]      * zv;           // 4 banks x broadcast
            s1 += Ms[mm * 64 + n0 + 32] * zv;
        }
        float* yp = y + (size_t)b * 8192 + ht * 16 + h;
        yp[(size_t)n0 * 128]        = s0;
        yp[(size_t)(n0 + 32) * 128] = s1;
    }
}

extern "C" void kernel_launch(void* const* d_in, const int* in_sizes, int n_in,
                              void* d_out, int out_size, void* d_ws, size_t ws_size,
                              hipStream_t stream) {
    const float* x    = (const float*)d_in[0];   // (2048, 2000) fp32
    const int*   ei   = (const int*)d_in[1];     // (2, 4096)
    const float* ew   = (const float*)d_in[2];   // (4096,)
    const float* W    = (const float*)d_in[3];   // (128, 2000) fp32
    const float* bias = (const float*)d_in[4];   // (128,)
    float* y = (float*)d_out;                    // (32, 64, 128) fp32

    float* Mt = (float*)d_ws;                    // 4096 f

    prep_M<<<16, 256, 0, stream>>>(ei, ew, Mt);
    gemm_fused<<<256, 512, 0, stream>>>(x, W, Mt, bias, y);
}